// Round 1
// baseline (104.898 us; speedup 1.0000x reference)
//
#include <hip/hip_runtime.h>
#include <float.h>

#define W  128
#define NB 50

__global__ __launch_bounds__(256) void mtf_kernel(const float* __restrict__ X,
                                                  float* __restrict__ out) {
    __shared__ int   bins[W];
    __shared__ int   hist[NB * NB];
    __shared__ int   rowsum[NB];
    __shared__ float probs[NB * NB];
    __shared__ float redmin[4], redmax[4];

    const int tid = threadIdx.x;
    const int s   = blockIdx.x;
    const float* xrow = X + (size_t)s * W;

    // ---- Phase 1: load + min/max reduction (wave = 64 lanes) ----
    float v = 0.0f;
    float vmin = FLT_MAX, vmax = -FLT_MAX;
    if (tid < W) { v = xrow[tid]; vmin = v; vmax = v; }
    #pragma unroll
    for (int off = 32; off >= 1; off >>= 1) {
        vmin = fminf(vmin, __shfl_down(vmin, off, 64));
        vmax = fmaxf(vmax, __shfl_down(vmax, off, 64));
    }
    if ((tid & 63) == 0) { redmin[tid >> 6] = vmin; redmax[tid >> 6] = vmax; }

    // zero histogram + rowsums while reduction lands
    for (int i = tid; i < NB * NB; i += 256) hist[i] = 0;
    if (tid < NB) rowsum[tid] = 0;
    __syncthreads();

    const float mn = fminf(fminf(redmin[0], redmin[1]), fminf(redmin[2], redmin[3]));
    const float mx = fmaxf(fmaxf(redmax[0], redmax[1]), fmaxf(redmax[2], redmax[3]));
    const float d  = (mx - mn) + 1e-6f;   // matches (X_max - X_min + EPS) in fp32

    // ---- Phase 2: bucketize (searchsorted side='left': #{edge < x}) ----
    if (tid < W) {
        float q   = (v - mn) / d;
        float xsc = q * 2.0f - 1.0f;      // *2 is exact; fma contraction harmless
        double xd = (double)xsc;
        int b = 0;
        #pragma unroll
        for (int k = 1; k <= NB - 1; ++k) {
            double bk = -1.0 + 0.04 * (double)k;   // linspace inner edges (fp64)
            b += (bk < xd) ? 1 : 0;
        }
        bins[tid] = b;
    }
    __syncthreads();

    // ---- Phase 3: transition histogram + row sums (LDS atomics) ----
    if (tid < W - 1) {
        int bi = bins[tid], bj = bins[tid + 1];
        atomicAdd(&hist[bi * NB + bj], 1);
        atomicAdd(&rowsum[bi], 1);
    }
    __syncthreads();

    // ---- Phase 4: row-normalize (exact fp32 division, empty-row guard) ----
    for (int i = tid; i < NB * NB; i += 256) {
        int rs = rowsum[i / NB];
        probs[i] = (float)hist[i] / (float)(rs == 0 ? 1 : rs);
    }
    __syncthreads();

    // ---- Phase 5: gather + coalesced float4 stores ----
    // Thread owns fixed 4-column chunk (bins cached in regs), walks 16 rows.
    float* orow = out + (size_t)s * W * W;
    const int c4 = (tid & 31) * 4;
    const int r0 = tid >> 5;
    const int b0 = bins[c4], b1 = bins[c4 + 1], b2 = bins[c4 + 2], b3 = bins[c4 + 3];
    #pragma unroll
    for (int it = 0; it < 16; ++it) {
        int row = r0 + it * 8;
        int rb  = bins[row] * NB;          // LDS broadcast across the half-wave
        float4 o;
        o.x = probs[rb + b0];
        o.y = probs[rb + b1];
        o.z = probs[rb + b2];
        o.w = probs[rb + b3];
        *(float4*)(orow + row * W + c4) = o;
    }
}

extern "C" void kernel_launch(void* const* d_in, const int* in_sizes, int n_in,
                              void* d_out, int out_size, void* d_ws, size_t ws_size,
                              hipStream_t stream) {
    const float* X = (const float*)d_in[0];
    float* out = (float*)d_out;
    int S = in_sizes[0] / W;               // 256*6 = 1536 series
    mtf_kernel<<<dim3(S), dim3(256), 0, stream>>>(X, out);
}